// Round 8
// baseline (364.176 us; speedup 1.0000x reference)
//
#include <hip/hip_runtime.h>
#include <cstdint>

#define NN 100000
#define EE 1600000
#define IN_F 512
#define HID_F 256
#define OUT_F 32
#define GSL 256          // blocks per XCD slice for fill
#define SLICE_W 12500    // NN / 8
#define CAP 64           // fixed CSR row capacity (deg ~ Poisson(16), P(>=64)<1e-20)

typedef float f32x4 __attribute__((ext_vector_type(4)));
typedef int   i32x4 __attribute__((ext_vector_type(4)));
typedef short s16x8 __attribute__((ext_vector_type(8)));
typedef uint32_t u32x4 __attribute__((ext_vector_type(4)));
typedef unsigned short u16;

static __device__ __forceinline__ u16 f2bf(float f) {
  uint32_t u = __builtin_bit_cast(uint32_t, f);
  u += 0x7FFFu + ((u >> 16) & 1u);   // round-to-nearest-even
  return (u16)(u >> 16);
}

static __device__ __forceinline__ float bf2f(u16 v) {
  uint32_t u = ((uint32_t)v) << 16;
  return __builtin_bit_cast(float, u);
}

// pack two f32 -> one u32 of 2 bf16 (RNE), dst.lo = src0
static __device__ __forceinline__ uint32_t pk_bf16(float a, float b) {
  uint32_t r;
  asm("v_cvt_pk_bf16_f32 %0, %1, %2" : "=v"(r) : "v"(a), "v"(b));
  return r;
}

// ---------------- fused prep ----------------
// W1S baked FRAGMENT-MAJOR for direct per-lane MFMA B-operand loads:
// u16 idx = (((kt*2+ks)*16 + fnG)*64 + lane)*8 + j holds w1[k][n],
//   k = kt*64 + ks*32 + (lane>>4)*8 + j,  n = fnG*16 + (lane&15)
// -> each fragment load is one coalesced 1KB read per wave.
__global__ __launch_bounds__(256) void k_prep(const float* __restrict__ w1,
                                              u16* __restrict__ w1s,
                                              const float* __restrict__ w2,
                                              u16* __restrict__ w2s,
                                              int* __restrict__ cur) {
  int b = blockIdx.x;
  int tid = threadIdx.x;
  if (b < 512) {                       // W1S fragment-major bake (131072 elems)
    int g = b * 256 + tid;
    int j    = g & 7;
    int lane = (g >> 3) & 63;
    int fnG  = (g >> 9) & 15;
    int kk   = g >> 13;                // kt*2+ks
    int l16 = lane & 15, lq = lane >> 4;
    int k = (kk >> 1) * 64 + (kk & 1) * 32 + lq * 8 + j;
    int n = fnG * 16 + l16;
    w1s[g] = f2bf(w1[k * HID_F + n]);
  } else if (b < 544) {                // W2S: [n=32][k=256] swizzled rows
    int g = (b - 512) * 256 + tid;     // 8192 elements
    int n  = g >> 8;
    int jp = g & 255;
    int kb = (jp * 2) ^ ((n & 7) << 4);
    int j  = kb >> 1;
    w2s[g] = f2bf(w2[j * OUT_F + n]);
  } else {                             // zero cur (degree counters)
    int i = (b - 544) * 256 + tid;
    if (i < NN) cur[i] = 0;
  }
}

// ---------------- graph build: ONE slice-local pass -> capacity CSR + degrees ----------------
__global__ __launch_bounds__(256) void k_fillC(const int* __restrict__ row,
                                               const int* __restrict__ col,
                                               int* __restrict__ cur,
                                               int* __restrict__ csr) {
  const int slice = blockIdx.x & 7;
  const int g = blockIdx.x >> 3;
  const unsigned lo = (unsigned)slice * SLICE_W, hi = lo + SLICE_W;
  const i32x4* c4 = (const i32x4*)col;
  const i32x4* r4 = (const i32x4*)row;
  for (int i = g * 256 + threadIdx.x; i < EE / 4; i += GSL * 256) {
    i32x4 c = c4[i];
    i32x4 r = r4[i];
    #pragma unroll
    for (int k = 0; k < 4; ++k) {
      unsigned cc = (unsigned)c[k];
      if (cc >= lo && cc < hi) {
        int p = atomicAdd(&cur[cc], 1);
        if (p < CAP) csr[(int)cc * CAP + p] = r[k];
      }
    }
  }
}

// ---------------- fused MLP: h = relu(x@W1+b1)@W2 + b2 ; also xs0 = bf16(dis*h) ----------------
// Barrier-free GEMM1: A fragments loaded per-lane direct from x (fp32->bf16 cvt in regs),
// B fragments direct from fragment-major w1s (coalesced, L2-hot). No LDS, no syncs in
// the K-loop; LDS only for the 2-barrier GEMM2 epilogue.
__global__ __launch_bounds__(512) void k_mlp(
    const float* __restrict__ x, const float* __restrict__ b1,
    const float* __restrict__ b2, const u16* __restrict__ w1s,
    const u16* __restrict__ w2s, const int* __restrict__ cnt,
    float* __restrict__ hout, u16* __restrict__ xs0) {
  __shared__ char smem[81920];
  char* h1L = smem;           // [128][512B] swizzled bf16 h1
  char* w2L = smem + 65536;   // [32][512B]  swizzled bf16 W2^T

  const int tid  = threadIdx.x;
  const int lane = tid & 63;
  const int wid  = tid >> 6;   // 0..7
  const int wm   = wid >> 2;   // 0..1
  const int wn   = wid & 3;    // 0..3
  const int l16  = lane & 15;
  const int lq   = lane >> 4;  // 0..3
  const int row0 = blockIdx.x * 128;

  {
    const char* src = (const char*)w2s;
    #pragma unroll
    for (int p = 0; p < 2; ++p) {
      int off = (p * 512 + tid) * 16;
      *(f32x4*)(w2L + off) = *(const f32x4*)(src + off);
    }
  }

  const f32x4 zf = {0.f, 0.f, 0.f, 0.f};
  f32x4 acc[4][4];
  #pragma unroll
  for (int i = 0; i < 4; ++i)
    #pragma unroll
    for (int j = 0; j < 4; ++j) acc[i][j] = zf;

  const int arow_base = row0 + wm * 64;

  for (int kt = 0; kt < IN_F / 64; ++kt) {
    #pragma unroll
    for (int ks = 0; ks < 2; ++ks) {
      const int kcol = kt * 64 + ks * 32 + lq * 8;
      s16x8 af[4], bf[4];
      #pragma unroll
      for (int fn = 0; fn < 4; ++fn) {
        const u16* src = w1s + ((size_t)(((kt * 2 + ks) * 16) + wn * 4 + fn) * 64 + lane) * 8;
        bf[fn] = *(const s16x8*)src;
      }
      #pragma unroll
      for (int fm = 0; fm < 4; ++fm) {
        int grow = arow_base + fm * 16 + l16;
        f32x4 a0 = zf, a1 = zf;
        if (grow < NN) {
          const float* xp = x + (size_t)grow * IN_F + kcol;
          a0 = *(const f32x4*)xp;
          a1 = *(const f32x4*)(xp + 4);
        }
        u32x4 pk;
        pk.x = pk_bf16(a0.x, a0.y);
        pk.y = pk_bf16(a0.z, a0.w);
        pk.z = pk_bf16(a1.x, a1.y);
        pk.w = pk_bf16(a1.z, a1.w);
        af[fm] = __builtin_bit_cast(s16x8, pk);
      }
      #pragma unroll
      for (int fm = 0; fm < 4; ++fm)
        #pragma unroll
        for (int fn = 0; fn < 4; ++fn)
          acc[fm][fn] = __builtin_amdgcn_mfma_f32_16x16x32_bf16(
              af[fm], bf[fn], acc[fm][fn], 0, 0, 0);
    }
  }

  float b1v[4];
  #pragma unroll
  for (int fn = 0; fn < 4; ++fn) b1v[fn] = b1[wn * 64 + fn * 16 + l16];

  // bias + relu -> h1L (bf16, swizzled)
  #pragma unroll
  for (int fm = 0; fm < 4; ++fm) {
    #pragma unroll
    for (int fn = 0; fn < 4; ++fn) {
      int col = wn * 64 + fn * 16 + l16;
      #pragma unroll
      for (int r = 0; r < 4; ++r) {
        int row = wm * 64 + fm * 16 + lq * 4 + r;
        float v = acc[fm][fn][r] + b1v[fn];
        v = fmaxf(v, 0.f);
        *(u16*)(h1L + row * 512 + ((col * 2) ^ ((row & 7) << 4))) = f2bf(v);
      }
    }
  }
  __syncthreads();

  f32x4 acc2[2];
  acc2[0] = zf; acc2[1] = zf;
  const int arow = wid * 16 + l16;
  #pragma unroll
  for (int ks = 0; ks < 8; ++ks) {
    int kb = ks * 64 + lq * 16;
    s16x8 af = *(const s16x8*)(h1L + arow * 512 + (kb ^ ((arow & 7) << 4)));
    #pragma unroll
    for (int fn = 0; fn < 2; ++fn) {
      int bn = fn * 16 + l16;
      s16x8 bf = *(const s16x8*)(w2L + bn * 512 + (kb ^ ((bn & 7) << 4)));
      acc2[fn] = __builtin_amdgcn_mfma_f32_16x16x32_bf16(af, bf, acc2[fn], 0, 0, 0);
    }
  }
  #pragma unroll
  for (int r = 0; r < 4; ++r) {
    int row = row0 + wid * 16 + lq * 4 + r;
    if (row >= NN) continue;
    float dr = rsqrtf((float)cnt[row] + 1.0f);
    #pragma unroll
    for (int fn = 0; fn < 2; ++fn) {
      int col = fn * 16 + l16;
      float v = acc2[fn][r] + b2[col];
      hout[(size_t)row * 32 + col] = v;
      xs0[(size_t)row * 32 + col] = f2bf(dr * v);
    }
  }
}

// ---------------- propagation: xk+1 = h + prox_l21(A_hat@xk - h) ----------------
// state xs = dis .* xk in bf16 (64B rows). one wave per node:
// 16 edge slots x 4 lanes x 16B (16 gathers in flight); capacity CSR rows at w*64.
template <int LAST>
__global__ __launch_bounds__(256) void k_prop(
    const u16* __restrict__ xs, const float* __restrict__ hh,
    u16* __restrict__ xs_out, float* __restrict__ fout,
    const int* __restrict__ cnt, const int* __restrict__ csr) {
  int w = blockIdx.x * 4 + (threadIdx.x >> 6);
  if (w >= NN) return;
  const int lane = threadIdx.x & 63;
  const int q = lane & 3;     // 8-feature slice
  const int s = lane >> 2;    // edge slot 0..15
  const int n = cnt[w];
  const int* __restrict__ crow = csr + (size_t)w * CAP;
  float acc[8] = {0.f, 0.f, 0.f, 0.f, 0.f, 0.f, 0.f, 0.f};
  for (int j = s; j < n; j += 16) {
    int src = crow[j];
    s16x8 v = *(const s16x8*)(xs + (size_t)src * 32 + q * 8);
    #pragma unroll
    for (int k = 0; k < 8; ++k) acc[k] += bf2f((u16)v[k]);
  }
  if (s == 0) {   // self-loop term
    s16x8 v = *(const s16x8*)(xs + (size_t)w * 32 + q * 8);
    #pragma unroll
    for (int k = 0; k < 8; ++k) acc[k] += bf2f((u16)v[k]);
  }
  #pragma unroll
  for (int m = 4; m <= 32; m <<= 1) {
    #pragma unroll
    for (int k = 0; k < 8; ++k) acc[k] += __shfl_xor(acc[k], m, 64);
  }
  const float di = rsqrtf((float)n + 1.0f);
  const f32x4 h0 = *(const f32x4*)(hh + (size_t)w * 32 + q * 8);
  const f32x4 h1 = *(const f32x4*)(hh + (size_t)w * 32 + q * 8 + 4);
  float hv[8] = {h0.x, h0.y, h0.z, h0.w, h1.x, h1.y, h1.z, h1.w};
  float d[8];
  float rn2 = 0.f;
  #pragma unroll
  for (int k = 0; k < 8; ++k) {
    d[k] = di * acc[k] - hv[k];
    rn2 += d[k] * d[k];
  }
  rn2 += __shfl_xor(rn2, 1, 64);
  rn2 += __shfl_xor(rn2, 2, 64);
  float rn = sqrtf(rn2);
  float sc = (rn > 0.f) ? fmaxf(rn - 0.5f, 0.f) / rn : 0.f;  // lam*gamma = 0.5
  if (s == 0) {
    if (LAST) {
      f32x4 o0, o1;
      o0.x = hv[0] + sc * d[0]; o0.y = hv[1] + sc * d[1];
      o0.z = hv[2] + sc * d[2]; o0.w = hv[3] + sc * d[3];
      o1.x = hv[4] + sc * d[4]; o1.y = hv[5] + sc * d[5];
      o1.z = hv[6] + sc * d[6]; o1.w = hv[7] + sc * d[7];
      *(f32x4*)(fout + (size_t)w * 32 + q * 8) = o0;
      *(f32x4*)(fout + (size_t)w * 32 + q * 8 + 4) = o1;
    } else {
      s16x8 o;
      #pragma unroll
      for (int k = 0; k < 8; ++k) o[k] = (short)f2bf(di * (hv[k] + sc * d[k]));
      *(s16x8*)(xs_out + (size_t)w * 32 + q * 8) = o;
    }
  }
}

// ---------------- launch ----------------
extern "C" void kernel_launch(void* const* d_in, const int* in_sizes, int n_in,
                              void* d_out, int out_size, void* d_ws, size_t ws_size,
                              hipStream_t stream) {
  const float* x  = (const float*)d_in[0];
  const float* W1 = (const float*)d_in[1];
  const float* b1 = (const float*)d_in[2];
  const float* W2 = (const float*)d_in[3];
  const float* b2 = (const float*)d_in[4];
  const int*   ei = (const int*)d_in[5];   // [2][E] int32

  char* ws = (char*)d_ws;
  float* h    = (float*)(ws);                  // 12.8 MB fp32
  u16*   xs0  = (u16*)  (ws + 12800000);       // 6.4 MB bf16 (dis.*xk)
  u16*   xs1  = (u16*)  (ws + 19200000);       // 6.4 MB bf16
  int*   csr  = (int*)  (ws + 25600000);       // 25.6 MB (capacity-64 rows)
  int*   cur  = (int*)  (ws + 51200000);       // 400 KB (degree counters)
  u16*   w1s  = (u16*)  (ws + 51600000);       // 256 KB
  u16*   w2s  = (u16*)  (ws + 51862144);       // 16 KB

  k_prep<<<935, 256, 0, stream>>>(W1, w1s, W2, w2s, cur);
  k_fillC<<<8 * GSL, 256, 0, stream>>>(ei, ei + EE, cur, csr);
  k_mlp<<<(NN + 127) / 128, 512, 0, stream>>>(x, b1, b2, w1s, w2s, cur, h, xs0);

  float* out = (float*)d_out;
  k_prop<0><<<(NN + 3) / 4, 256, 0, stream>>>(xs0, h, xs1, nullptr, cur, csr);
  k_prop<0><<<(NN + 3) / 4, 256, 0, stream>>>(xs1, h, xs0, nullptr, cur, csr);
  k_prop<1><<<(NN + 3) / 4, 256, 0, stream>>>(xs0, h, nullptr, out,  cur, csr);
}

// Round 9
// 296.399 us; speedup vs baseline: 1.2287x; 1.2287x over previous
//
#include <hip/hip_runtime.h>
#include <cstdint>

#define NN 100000
#define EE 1600000
#define IN_F 512
#define HID_F 256
#define OUT_F 32
#define GSL 256          // blocks per XCD slice for fill
#define SLICE_W 12500    // NN / 8
#define CAP 64           // fixed CSR row capacity (deg ~ Poisson(16), P(>=64)<1e-20)

typedef float f32x4 __attribute__((ext_vector_type(4)));
typedef int   i32x4 __attribute__((ext_vector_type(4)));
typedef short s16x8 __attribute__((ext_vector_type(8)));
typedef uint32_t u32x4 __attribute__((ext_vector_type(4)));
typedef unsigned short u16;

static __device__ __forceinline__ u16 f2bf(float f) {
  uint32_t u = __builtin_bit_cast(uint32_t, f);
  u += 0x7FFFu + ((u >> 16) & 1u);   // round-to-nearest-even
  return (u16)(u >> 16);
}

static __device__ __forceinline__ float bf2f(u16 v) {
  uint32_t u = ((uint32_t)v) << 16;
  return __builtin_bit_cast(float, u);
}

// pack two f32 -> one u32 of 2 bf16 (RNE), dst.lo = src0
static __device__ __forceinline__ uint32_t pk_bf16(float a, float b) {
  uint32_t r;
  asm("v_cvt_pk_bf16_f32 %0, %1, %2" : "=v"(r) : "v"(a), "v"(b));
  return r;
}

// ---------------- fused prep ----------------
// W1F fragment-major: u16 idx = ((kk*16 + fnG)*64 + lane)*8 + j  holds w1[k][n],
//   kk = kt*2+ks (0..15), k = kk*32 + (lane>>4)*8 + j, n = fnG*16 + (lane&15)
// W2F fragment-major: u16 idx = ((ks*2+fn)*64 + lane)*8 + j holds w2[k][n],
//   k = ks*32 + (lane>>4)*8 + j, n = fn*16 + (lane&15)
// -> every B-fragment load is one coalesced 1KB wave read from L2.
__global__ __launch_bounds__(256) void k_prep(const float* __restrict__ w1,
                                              u16* __restrict__ w1f,
                                              const float* __restrict__ w2,
                                              u16* __restrict__ w2f,
                                              int* __restrict__ cur) {
  int b = blockIdx.x;
  int tid = threadIdx.x;
  if (b < 512) {                       // W1F bake (131072 elems)
    int g = b * 256 + tid;
    int j    = g & 7;
    int lane = (g >> 3) & 63;
    int fnG  = (g >> 9) & 15;
    int kk   = g >> 13;
    int k = kk * 32 + (lane >> 4) * 8 + j;
    int n = fnG * 16 + (lane & 15);
    w1f[g] = f2bf(w1[k * HID_F + n]);
  } else if (b < 544) {                // W2F bake (8192 elems)
    int g = (b - 512) * 256 + tid;
    int j    = g & 7;
    int lane = (g >> 3) & 63;
    int ff   = g >> 9;                 // ks*2+fn (0..15)
    int k = (ff >> 1) * 32 + (lane >> 4) * 8 + j;
    int n = (ff & 1) * 16 + (lane & 15);
    w2f[g] = f2bf(w2[k * OUT_F + n]);
  } else {                             // zero cur (degree counters)
    int i = (b - 544) * 256 + tid;
    if (i < NN) cur[i] = 0;
  }
}

// ---------------- graph build: ONE slice-local pass -> capacity CSR + degrees ----------------
__global__ __launch_bounds__(256) void k_fillC(const int* __restrict__ row,
                                               const int* __restrict__ col,
                                               int* __restrict__ cur,
                                               int* __restrict__ csr) {
  const int slice = blockIdx.x & 7;
  const int g = blockIdx.x >> 3;
  const unsigned lo = (unsigned)slice * SLICE_W, hi = lo + SLICE_W;
  const i32x4* c4 = (const i32x4*)col;
  const i32x4* r4 = (const i32x4*)row;
  for (int i = g * 256 + threadIdx.x; i < EE / 4; i += GSL * 256) {
    i32x4 c = c4[i];
    i32x4 r = r4[i];
    #pragma unroll
    for (int k = 0; k < 4; ++k) {
      unsigned cc = (unsigned)c[k];
      if (cc >= lo && cc < hi) {
        int p = atomicAdd(&cur[cc], 1);
        if (p < CAP) csr[(int)cc * CAP + p] = r[k];
      }
    }
  }
}

// ---------------- fused MLP: h = relu(x@W1+b1)@W2 + b2 ; also xs0 = bf16(dis*h) ----------------
// Stage-once design: whole 128x512 x-row-block -> bf16 LDS (128KB, XOR-swizzled 16B slots)
// with coalesced 2KB-row reads. K-loop has ZERO barriers: ds_read(A) + fragment-major
// coalesced L2 loads (B, reg-prefetched) + MFMA. 3 barriers total in the kernel.
__global__ __launch_bounds__(512) void k_mlp(
    const float* __restrict__ x, const float* __restrict__ b1,
    const float* __restrict__ b2, const u16* __restrict__ w1f,
    const u16* __restrict__ w2f, const int* __restrict__ cnt,
    float* __restrict__ hout, u16* __restrict__ xs0) {
  __shared__ char smem[131072];
  char* aL  = smem;           // [128 rows][64 slots x 16B], slot ^= (row&7)
  char* h1L = smem;           // [128][512B] swizzled bf16 h1 (aliases aL, post K-loop)

  const int tid  = threadIdx.x;
  const int lane = tid & 63;
  const int wid  = tid >> 6;   // 0..7
  const int wm   = wid >> 2;   // 0..1
  const int wn   = wid & 3;    // 0..3
  const int l16  = lane & 15;
  const int lq   = lane >> 4;  // 0..3
  const int row0 = blockIdx.x * 128;

  const f32x4 zf = {0.f, 0.f, 0.f, 0.f};

  // ---- stage A once: wave wid stages rows wid*16..wid*16+15 (coalesced 2KB/row)
  #pragma unroll
  for (int rr = 0; rr < 16; ++rr) {
    int row  = wid * 16 + rr;
    int grow = row0 + row;
    f32x4 a0 = zf, a1 = zf;
    if (grow < NN) {
      const float* xp = x + (size_t)grow * IN_F + lane * 8;
      a0 = *(const f32x4*)xp;
      a1 = *(const f32x4*)(xp + 4);
    }
    u32x4 pk;
    pk.x = pk_bf16(a0.x, a0.y);
    pk.y = pk_bf16(a0.z, a0.w);
    pk.z = pk_bf16(a1.x, a1.y);
    pk.w = pk_bf16(a1.z, a1.w);
    int slot = lane ^ (row & 7);
    *(u32x4*)(aL + row * 1024 + slot * 16) = pk;
  }
  __syncthreads();

  f32x4 acc[4][4];
  #pragma unroll
  for (int i = 0; i < 4; ++i)
    #pragma unroll
    for (int j = 0; j < 4; ++j) acc[i][j] = zf;

  const int abase = wm * 64;

  s16x8 bf[4], bfn[4];
  #pragma unroll
  for (int fn = 0; fn < 4; ++fn)
    bf[fn] = *(const s16x8*)(w1f + ((size_t)(0 * 16 + wn * 4 + fn) * 64 + lane) * 8);

  #pragma unroll
  for (int kk = 0; kk < 16; ++kk) {      // kk = kt*2+ks, K=32 per step
    if (kk < 15) {
      #pragma unroll
      for (int fn = 0; fn < 4; ++fn)
        bfn[fn] = *(const s16x8*)(w1f + ((size_t)((kk + 1) * 16 + wn * 4 + fn) * 64 + lane) * 8);
    }
    s16x8 af[4];
    #pragma unroll
    for (int fm = 0; fm < 4; ++fm) {
      int row  = abase + fm * 16 + l16;
      int slot = (kk * 4 + lq) ^ (row & 7);
      af[fm] = *(const s16x8*)(aL + row * 1024 + slot * 16);
    }
    #pragma unroll
    for (int fm = 0; fm < 4; ++fm)
      #pragma unroll
      for (int fn = 0; fn < 4; ++fn)
        acc[fm][fn] = __builtin_amdgcn_mfma_f32_16x16x32_bf16(
            af[fm], bf[fn], acc[fm][fn], 0, 0, 0);
    #pragma unroll
    for (int fn = 0; fn < 4; ++fn) bf[fn] = bfn[fn];
  }

  float b1v[4];
  #pragma unroll
  for (int fn = 0; fn < 4; ++fn) b1v[fn] = b1[wn * 64 + fn * 16 + l16];

  __syncthreads();   // all waves done reading aL
  // bias + relu -> h1L (bf16, swizzled)
  #pragma unroll
  for (int fm = 0; fm < 4; ++fm) {
    #pragma unroll
    for (int fn = 0; fn < 4; ++fn) {
      int col = wn * 64 + fn * 16 + l16;
      #pragma unroll
      for (int r = 0; r < 4; ++r) {
        int row = wm * 64 + fm * 16 + lq * 4 + r;
        float v = acc[fm][fn][r] + b1v[fn];
        v = fmaxf(v, 0.f);
        *(u16*)(h1L + row * 512 + ((col * 2) ^ ((row & 7) << 4))) = f2bf(v);
      }
    }
  }
  __syncthreads();

  // GEMM2: [128x256]@[256x32]; A from h1L, B fragment-major direct from L2
  f32x4 acc2[2];
  acc2[0] = zf; acc2[1] = zf;
  const int arow = wid * 16 + l16;
  #pragma unroll
  for (int ks = 0; ks < 8; ++ks) {
    int kb = ks * 64 + lq * 16;
    s16x8 af = *(const s16x8*)(h1L + arow * 512 + (kb ^ ((arow & 7) << 4)));
    #pragma unroll
    for (int fn = 0; fn < 2; ++fn) {
      s16x8 bfr = *(const s16x8*)(w2f + ((size_t)((ks * 2 + fn) * 64) + lane) * 8);
      acc2[fn] = __builtin_amdgcn_mfma_f32_16x16x32_bf16(af, bfr, acc2[fn], 0, 0, 0);
    }
  }
  #pragma unroll
  for (int r = 0; r < 4; ++r) {
    int row = row0 + wid * 16 + lq * 4 + r;
    if (row >= NN) continue;
    float dr = rsqrtf((float)cnt[row] + 1.0f);
    #pragma unroll
    for (int fn = 0; fn < 2; ++fn) {
      int col = fn * 16 + l16;
      float v = acc2[fn][r] + b2[col];
      hout[(size_t)row * 32 + col] = v;
      xs0[(size_t)row * 32 + col] = f2bf(dr * v);
    }
  }
}

// ---------------- propagation: xk+1 = h + prox_l21(A_hat@xk - h) ----------------
// state xs = dis .* xk in bf16 (64B rows). one wave per node:
// 16 edge slots x 4 lanes x 16B (16 gathers in flight); capacity CSR rows at w*64.
template <int LAST>
__global__ __launch_bounds__(256) void k_prop(
    const u16* __restrict__ xs, const float* __restrict__ hh,
    u16* __restrict__ xs_out, float* __restrict__ fout,
    const int* __restrict__ cnt, const int* __restrict__ csr) {
  int w = blockIdx.x * 4 + (threadIdx.x >> 6);
  if (w >= NN) return;
  const int lane = threadIdx.x & 63;
  const int q = lane & 3;     // 8-feature slice
  const int s = lane >> 2;    // edge slot 0..15
  const int n = cnt[w];
  const int* __restrict__ crow = csr + (size_t)w * CAP;
  float acc[8] = {0.f, 0.f, 0.f, 0.f, 0.f, 0.f, 0.f, 0.f};
  for (int j = s; j < n; j += 16) {
    int src = crow[j];
    s16x8 v = *(const s16x8*)(xs + (size_t)src * 32 + q * 8);
    #pragma unroll
    for (int k = 0; k < 8; ++k) acc[k] += bf2f((u16)v[k]);
  }
  if (s == 0) {   // self-loop term
    s16x8 v = *(const s16x8*)(xs + (size_t)w * 32 + q * 8);
    #pragma unroll
    for (int k = 0; k < 8; ++k) acc[k] += bf2f((u16)v[k]);
  }
  #pragma unroll
  for (int m = 4; m <= 32; m <<= 1) {
    #pragma unroll
    for (int k = 0; k < 8; ++k) acc[k] += __shfl_xor(acc[k], m, 64);
  }
  const float di = rsqrtf((float)n + 1.0f);
  const f32x4 h0 = *(const f32x4*)(hh + (size_t)w * 32 + q * 8);
  const f32x4 h1 = *(const f32x4*)(hh + (size_t)w * 32 + q * 8 + 4);
  float hv[8] = {h0.x, h0.y, h0.z, h0.w, h1.x, h1.y, h1.z, h1.w};
  float d[8];
  float rn2 = 0.f;
  #pragma unroll
  for (int k = 0; k < 8; ++k) {
    d[k] = di * acc[k] - hv[k];
    rn2 += d[k] * d[k];
  }
  rn2 += __shfl_xor(rn2, 1, 64);
  rn2 += __shfl_xor(rn2, 2, 64);
  float rn = sqrtf(rn2);
  float sc = (rn > 0.f) ? fmaxf(rn - 0.5f, 0.f) / rn : 0.f;  // lam*gamma = 0.5
  if (s == 0) {
    if (LAST) {
      f32x4 o0, o1;
      o0.x = hv[0] + sc * d[0]; o0.y = hv[1] + sc * d[1];
      o0.z = hv[2] + sc * d[2]; o0.w = hv[3] + sc * d[3];
      o1.x = hv[4] + sc * d[4]; o1.y = hv[5] + sc * d[5];
      o1.z = hv[6] + sc * d[6]; o1.w = hv[7] + sc * d[7];
      *(f32x4*)(fout + (size_t)w * 32 + q * 8) = o0;
      *(f32x4*)(fout + (size_t)w * 32 + q * 8 + 4) = o1;
    } else {
      s16x8 o;
      #pragma unroll
      for (int k = 0; k < 8; ++k) o[k] = (short)f2bf(di * (hv[k] + sc * d[k]));
      *(s16x8*)(xs_out + (size_t)w * 32 + q * 8) = o;
    }
  }
}

// ---------------- launch ----------------
extern "C" void kernel_launch(void* const* d_in, const int* in_sizes, int n_in,
                              void* d_out, int out_size, void* d_ws, size_t ws_size,
                              hipStream_t stream) {
  const float* x  = (const float*)d_in[0];
  const float* W1 = (const float*)d_in[1];
  const float* b1 = (const float*)d_in[2];
  const float* W2 = (const float*)d_in[3];
  const float* b2 = (const float*)d_in[4];
  const int*   ei = (const int*)d_in[5];   // [2][E] int32

  char* ws = (char*)d_ws;
  float* h    = (float*)(ws);                  // 12.8 MB fp32
  u16*   xs0  = (u16*)  (ws + 12800000);       // 6.4 MB bf16 (dis.*xk)
  u16*   xs1  = (u16*)  (ws + 19200000);       // 6.4 MB bf16
  int*   csr  = (int*)  (ws + 25600000);       // 25.6 MB (capacity-64 rows)
  int*   cur  = (int*)  (ws + 51200000);       // 400 KB (degree counters)
  u16*   w1f  = (u16*)  (ws + 51600000);       // 256 KB
  u16*   w2f  = (u16*)  (ws + 51862144);       // 16 KB

  k_prep<<<935, 256, 0, stream>>>(W1, w1f, W2, w2f, cur);
  k_fillC<<<8 * GSL, 256, 0, stream>>>(ei, ei + EE, cur, csr);
  k_mlp<<<(NN + 127) / 128, 512, 0, stream>>>(x, b1, b2, w1f, w2f, cur, h, xs0);

  float* out = (float*)d_out;
  k_prop<0><<<(NN + 3) / 4, 256, 0, stream>>>(xs0, h, xs1, nullptr, cur, csr);
  k_prop<0><<<(NN + 3) / 4, 256, 0, stream>>>(xs1, h, xs0, nullptr, cur, csr);
  k_prop<1><<<(NN + 3) / 4, 256, 0, stream>>>(xs0, h, nullptr, out,  cur, csr);
}

// Round 10
// 276.663 us; speedup vs baseline: 1.3163x; 1.0713x over previous
//
#include <hip/hip_runtime.h>
#include <cstdint>

#define NN 100000
#define EE 1600000
#define IN_F 512
#define HID_F 256
#define OUT_F 32
#define GSL 256          // blocks per XCD slice for fill
#define SLICE_W 12500    // NN / 8
#define CAP 64           // fixed CSR row capacity (deg ~ Poisson(16), P(>=64)<1e-20)

typedef float f32x4 __attribute__((ext_vector_type(4)));
typedef int   i32x4 __attribute__((ext_vector_type(4)));
typedef short s16x8 __attribute__((ext_vector_type(8)));
typedef uint32_t u32x4 __attribute__((ext_vector_type(4)));
typedef unsigned short u16;

static __device__ __forceinline__ u16 f2bf(float f) {
  uint32_t u = __builtin_bit_cast(uint32_t, f);
  u += 0x7FFFu + ((u >> 16) & 1u);   // round-to-nearest-even
  return (u16)(u >> 16);
}

static __device__ __forceinline__ float bf2f(u16 v) {
  uint32_t u = ((uint32_t)v) << 16;
  return __builtin_bit_cast(float, u);
}

// pack two f32 -> one u32 of 2 bf16 (RNE), dst.lo = src0
static __device__ __forceinline__ uint32_t pk_bf16(float a, float b) {
  uint32_t r;
  asm("v_cvt_pk_bf16_f32 %0, %1, %2" : "=v"(r) : "v"(a), "v"(b));
  return r;
}

// ---------------- fused prep ----------------
// W1F fragment-major: u16 idx = ((kk*16 + fnG)*64 + lane)*8 + j  holds w1[k][n],
//   kk = kt*2+ks (0..15), k = kk*32 + (lane>>4)*8 + j, n = fnG*16 + (lane&15)
// W2F fragment-major: u16 idx = ((ks*2+fn)*64 + lane)*8 + j holds w2[k][n]
// -> every B-fragment load is one coalesced 1KB wave read from L2.
__global__ __launch_bounds__(256) void k_prep(const float* __restrict__ w1,
                                              u16* __restrict__ w1f,
                                              const float* __restrict__ w2,
                                              u16* __restrict__ w2f,
                                              int* __restrict__ cur) {
  int b = blockIdx.x;
  int tid = threadIdx.x;
  if (b < 512) {                       // W1F bake (131072 elems)
    int g = b * 256 + tid;
    int j    = g & 7;
    int lane = (g >> 3) & 63;
    int fnG  = (g >> 9) & 15;
    int kk   = g >> 13;
    int k = kk * 32 + (lane >> 4) * 8 + j;
    int n = fnG * 16 + (lane & 15);
    w1f[g] = f2bf(w1[k * HID_F + n]);
  } else if (b < 544) {                // W2F bake (8192 elems)
    int g = (b - 512) * 256 + tid;
    int j    = g & 7;
    int lane = (g >> 3) & 63;
    int ff   = g >> 9;                 // ks*2+fn (0..15)
    int k = (ff >> 1) * 32 + (lane >> 4) * 8 + j;
    int n = (ff & 1) * 16 + (lane & 15);
    w2f[g] = f2bf(w2[k * OUT_F + n]);
  } else {                             // zero cur (degree counters)
    int i = (b - 544) * 256 + tid;
    if (i < NN) cur[i] = 0;
  }
}

// ---------------- graph build: ONE slice-local pass -> capacity CSR + degrees ----------------
__global__ __launch_bounds__(256) void k_fillC(const int* __restrict__ row,
                                               const int* __restrict__ col,
                                               int* __restrict__ cur,
                                               int* __restrict__ csr) {
  const int slice = blockIdx.x & 7;
  const int g = blockIdx.x >> 3;
  const unsigned lo = (unsigned)slice * SLICE_W, hi = lo + SLICE_W;
  const i32x4* c4 = (const i32x4*)col;
  const i32x4* r4 = (const i32x4*)row;
  for (int i = g * 256 + threadIdx.x; i < EE / 4; i += GSL * 256) {
    i32x4 c = c4[i];
    i32x4 r = r4[i];
    #pragma unroll
    for (int k = 0; k < 4; ++k) {
      unsigned cc = (unsigned)c[k];
      if (cc >= lo && cc < hi) {
        int p = atomicAdd(&cur[cc], 1);
        if (p < CAP) csr[(int)cc * CAP + p] = r[k];
      }
    }
  }
}

// ---------------- fused MLP: h = relu(x@W1+b1)@W2 + b2 ; also xs0 = bf16(dis*h) ----------------
// BM=64, 256 threads (4 waves), LDS 32KB -> 4-5 blocks/CU (occupancy-first design).
// A: K-tiled 8KB LDS tiles (2 barriers/kt, 4-wave scope). B/W2: fragment-major direct
// from L2 (coalesced 1KB wave reads, L2-hot 256KB/16KB).
__global__ __launch_bounds__(256, 4) void k_mlp(
    const float* __restrict__ x, const float* __restrict__ b1,
    const float* __restrict__ b2, const u16* __restrict__ w1f,
    const u16* __restrict__ w2f, const int* __restrict__ cnt,
    float* __restrict__ hout, u16* __restrict__ xs0) {
  __shared__ char smem[32768];
  char* aL  = smem;           // [64 rows][128B] swizzled bf16 A k-tile (K-loop)
  char* h1L = smem;           // [64 rows][512B] swizzled bf16 h1 (aliases aL post-loop)

  const int tid  = threadIdx.x;
  const int lane = tid & 63;
  const int wid  = tid >> 6;   // 0..3
  const int wn   = wid;        // col quarter (64 cols)
  const int l16  = lane & 15;
  const int lq   = lane >> 4;  // 0..3
  const int row0 = blockIdx.x * 64;

  const f32x4 zf = {0.f, 0.f, 0.f, 0.f};
  f32x4 acc[4][4];
  #pragma unroll
  for (int i = 0; i < 4; ++i)
    #pragma unroll
    for (int j = 0; j < 4; ++j) acc[i][j] = zf;

  for (int kt = 0; kt < IN_F / 64; ++kt) {
    __syncthreads();                   // previous tile fully consumed
    // stage A k-tile: 64 rows x 64 cols fp32 -> bf16 swizzled (coalesced 16B reads)
    #pragma unroll
    for (int p = 0; p < 4; ++p) {
      int v   = p * 256 + tid;         // 1024 granules
      int row = v >> 4;                // 0..63
      int f4  = v & 15;
      int grow = row0 + row;
      f32x4 xv = zf;
      if (grow < NN)
        xv = *(const f32x4*)(x + (size_t)grow * IN_F + kt * 64 + f4 * 4);
      uint32_t lo = pk_bf16(xv.x, xv.y);
      uint32_t hi = pk_bf16(xv.z, xv.w);
      uint64_t wv = (uint64_t)lo | ((uint64_t)hi << 32);
      int kb = (f4 * 8) ^ ((row & 7) << 4);
      *(uint64_t*)(aL + row * 128 + kb) = wv;
    }
    __syncthreads();
    #pragma unroll
    for (int ks = 0; ks < 2; ++ks) {
      const int kk = kt * 2 + ks;
      s16x8 af[4], bf[4];
      #pragma unroll
      for (int fn = 0; fn < 4; ++fn)
        bf[fn] = *(const s16x8*)(w1f + ((size_t)(kk * 16 + wn * 4 + fn) * 64 + lane) * 8);
      #pragma unroll
      for (int fm = 0; fm < 4; ++fm) {
        int row = fm * 16 + l16;
        int kb  = (ks * 64 + lq * 16) ^ ((row & 7) << 4);
        af[fm] = *(const s16x8*)(aL + row * 128 + kb);
      }
      #pragma unroll
      for (int fm = 0; fm < 4; ++fm)
        #pragma unroll
        for (int fn = 0; fn < 4; ++fn)
          acc[fm][fn] = __builtin_amdgcn_mfma_f32_16x16x32_bf16(
              af[fm], bf[fn], acc[fm][fn], 0, 0, 0);
    }
  }

  float b1v[4];
  #pragma unroll
  for (int fn = 0; fn < 4; ++fn) b1v[fn] = b1[wn * 64 + fn * 16 + l16];

  __syncthreads();   // aL fully consumed; safe to write h1L (alias)
  // bias + relu -> h1L (bf16, swizzled)
  #pragma unroll
  for (int fm = 0; fm < 4; ++fm) {
    #pragma unroll
    for (int fn = 0; fn < 4; ++fn) {
      int col = wn * 64 + fn * 16 + l16;
      #pragma unroll
      for (int r = 0; r < 4; ++r) {
        int row = fm * 16 + lq * 4 + r;
        float v = acc[fm][fn][r] + b1v[fn];
        v = fmaxf(v, 0.f);
        *(u16*)(h1L + row * 512 + ((col * 2) ^ ((row & 7) << 4))) = f2bf(v);
      }
    }
  }
  __syncthreads();

  // GEMM2: [64x256]@[256x32]; A from h1L, B fragment-major direct from L2
  f32x4 acc2[2];
  acc2[0] = zf; acc2[1] = zf;
  const int arow = wid * 16 + l16;
  #pragma unroll
  for (int ks = 0; ks < 8; ++ks) {
    int kb = ks * 64 + lq * 16;
    s16x8 af = *(const s16x8*)(h1L + arow * 512 + (kb ^ ((arow & 7) << 4)));
    #pragma unroll
    for (int fn = 0; fn < 2; ++fn) {
      s16x8 bfr = *(const s16x8*)(w2f + ((size_t)((ks * 2 + fn) * 64) + lane) * 8);
      acc2[fn] = __builtin_amdgcn_mfma_f32_16x16x32_bf16(af, bfr, acc2[fn], 0, 0, 0);
    }
  }
  #pragma unroll
  for (int r = 0; r < 4; ++r) {
    int row = row0 + wid * 16 + lq * 4 + r;
    if (row >= NN) continue;
    float dr = rsqrtf((float)cnt[row] + 1.0f);
    #pragma unroll
    for (int fn = 0; fn < 2; ++fn) {
      int col = fn * 16 + l16;
      float v = acc2[fn][r] + b2[col];
      hout[(size_t)row * 32 + col] = v;
      xs0[(size_t)row * 32 + col] = f2bf(dr * v);
    }
  }
}

// ---------------- propagation: xk+1 = h + prox_l21(A_hat@xk - h) ----------------
// state xs = dis .* xk in bf16 (64B rows). one wave per node:
// 16 edge slots x 4 lanes x 16B (16 gathers in flight); capacity CSR rows at w*64.
template <int LAST>
__global__ __launch_bounds__(256) void k_prop(
    const u16* __restrict__ xs, const float* __restrict__ hh,
    u16* __restrict__ xs_out, float* __restrict__ fout,
    const int* __restrict__ cnt, const int* __restrict__ csr) {
  int w = blockIdx.x * 4 + (threadIdx.x >> 6);
  if (w >= NN) return;
  const int lane = threadIdx.x & 63;
  const int q = lane & 3;     // 8-feature slice
  const int s = lane >> 2;    // edge slot 0..15
  const int n = cnt[w];
  const int* __restrict__ crow = csr + (size_t)w * CAP;
  float acc[8] = {0.f, 0.f, 0.f, 0.f, 0.f, 0.f, 0.f, 0.f};
  for (int j = s; j < n; j += 16) {
    int src = crow[j];
    s16x8 v = *(const s16x8*)(xs + (size_t)src * 32 + q * 8);
    #pragma unroll
    for (int k = 0; k < 8; ++k) acc[k] += bf2f((u16)v[k]);
  }
  if (s == 0) {   // self-loop term
    s16x8 v = *(const s16x8*)(xs + (size_t)w * 32 + q * 8);
    #pragma unroll
    for (int k = 0; k < 8; ++k) acc[k] += bf2f((u16)v[k]);
  }
  #pragma unroll
  for (int m = 4; m <= 32; m <<= 1) {
    #pragma unroll
    for (int k = 0; k < 8; ++k) acc[k] += __shfl_xor(acc[k], m, 64);
  }
  const float di = rsqrtf((float)n + 1.0f);
  const f32x4 h0 = *(const f32x4*)(hh + (size_t)w * 32 + q * 8);
  const f32x4 h1 = *(const f32x4*)(hh + (size_t)w * 32 + q * 8 + 4);
  float hv[8] = {h0.x, h0.y, h0.z, h0.w, h1.x, h1.y, h1.z, h1.w};
  float d[8];
  float rn2 = 0.f;
  #pragma unroll
  for (int k = 0; k < 8; ++k) {
    d[k] = di * acc[k] - hv[k];
    rn2 += d[k] * d[k];
  }
  rn2 += __shfl_xor(rn2, 1, 64);
  rn2 += __shfl_xor(rn2, 2, 64);
  float rn = sqrtf(rn2);
  float sc = (rn > 0.f) ? fmaxf(rn - 0.5f, 0.f) / rn : 0.f;  // lam*gamma = 0.5
  if (s == 0) {
    if (LAST) {
      f32x4 o0, o1;
      o0.x = hv[0] + sc * d[0]; o0.y = hv[1] + sc * d[1];
      o0.z = hv[2] + sc * d[2]; o0.w = hv[3] + sc * d[3];
      o1.x = hv[4] + sc * d[4]; o1.y = hv[5] + sc * d[5];
      o1.z = hv[6] + sc * d[6]; o1.w = hv[7] + sc * d[7];
      *(f32x4*)(fout + (size_t)w * 32 + q * 8) = o0;
      *(f32x4*)(fout + (size_t)w * 32 + q * 8 + 4) = o1;
    } else {
      s16x8 o;
      #pragma unroll
      for (int k = 0; k < 8; ++k) o[k] = (short)f2bf(di * (hv[k] + sc * d[k]));
      *(s16x8*)(xs_out + (size_t)w * 32 + q * 8) = o;
    }
  }
}

// ---------------- launch ----------------
extern "C" void kernel_launch(void* const* d_in, const int* in_sizes, int n_in,
                              void* d_out, int out_size, void* d_ws, size_t ws_size,
                              hipStream_t stream) {
  const float* x  = (const float*)d_in[0];
  const float* W1 = (const float*)d_in[1];
  const float* b1 = (const float*)d_in[2];
  const float* W2 = (const float*)d_in[3];
  const float* b2 = (const float*)d_in[4];
  const int*   ei = (const int*)d_in[5];   // [2][E] int32

  char* ws = (char*)d_ws;
  float* h    = (float*)(ws);                  // 12.8 MB fp32
  u16*   xs0  = (u16*)  (ws + 12800000);       // 6.4 MB bf16 (dis.*xk)
  u16*   xs1  = (u16*)  (ws + 19200000);       // 6.4 MB bf16
  int*   csr  = (int*)  (ws + 25600000);       // 25.6 MB (capacity-64 rows)
  int*   cur  = (int*)  (ws + 51200000);       // 400 KB (degree counters)
  u16*   w1f  = (u16*)  (ws + 51600000);       // 256 KB
  u16*   w2f  = (u16*)  (ws + 51862144);       // 16 KB

  k_prep<<<935, 256, 0, stream>>>(W1, w1f, W2, w2f, cur);
  k_fillC<<<8 * GSL, 256, 0, stream>>>(ei, ei + EE, cur, csr);
  k_mlp<<<(NN + 63) / 64, 256, 0, stream>>>(x, b1, b2, w1f, w2f, cur, h, xs0);

  float* out = (float*)d_out;
  k_prop<0><<<(NN + 3) / 4, 256, 0, stream>>>(xs0, h, xs1, nullptr, cur, csr);
  k_prop<0><<<(NN + 3) / 4, 256, 0, stream>>>(xs1, h, xs0, nullptr, cur, csr);
  k_prop<1><<<(NN + 3) / 4, 256, 0, stream>>>(xs0, h, nullptr, out,  cur, csr);
}